// Round 2
// baseline (2735.461 us; speedup 1.0000x reference)
//
#include <hip/hip_runtime.h>
#include <hip/hip_bf16.h>
#include <math.h>

#define NU 50000
#define NFOOD 30000
#define NING 20000
#define NCAT 5000
#define NHAB 10000
#define NNODES 115000
#define NREL 8
#define NEDGE 1500000
#define H2COLS 18     // 8*2 + root(2)

static inline size_t alignup(size_t x) { return (x + 255) & ~(size_t)255; }

__device__ inline float bf16_bits_to_f32(unsigned short u) {
  return __uint_as_float(((unsigned)u) << 16);
}
__device__ inline unsigned short f32_to_bf16_bits(float f) {
  unsigned u = __float_as_uint(f);
  unsigned r = u + 0x7fffu + ((u >> 16) & 1u);
  return (unsigned short)(r >> 16);
}

// ---------------- generic tiled fp32 GEMM: C[M,N] = A[M,K] @ B[K,N] (+bias) ---------
// 64x64 tile, BK=16, 256 threads, 4x4 microtile. K%16==0, N%64==0 assumed.
template <bool OUT_BF16>
__global__ __launch_bounds__(256) void gemm64(const float* __restrict__ A,
                                              const float* __restrict__ B,
                                              const float* __restrict__ bias,
                                              void* __restrict__ Cv,
                                              int M, int N, int K) {
  __shared__ float As[16][65];
  __shared__ float Bs[16][65];
  const int bm = blockIdx.y * 64;
  const int bn = blockIdx.x * 64;
  const int tid = threadIdx.x;
  const int tm = (tid >> 4) << 2;
  const int tn = (tid & 15) << 2;
  const int ar = tid >> 2;          // 0..63 (A row in tile)
  const int ac = (tid & 3) << 2;    // 0,4,8,12 (A col in tile)
  const int br = tid >> 4;          // 0..15 (B row in tile)
  const int bc = (tid & 15) << 2;   // 0..60 (B col in tile)
  float acc[4][4] = {};
  for (int k0 = 0; k0 < K; k0 += 16) {
    float4 a;
    if (bm + ar < M) a = *(const float4*)(A + (size_t)(bm + ar) * K + k0 + ac);
    else a = make_float4(0.f, 0.f, 0.f, 0.f);
    As[ac + 0][ar] = a.x;
    As[ac + 1][ar] = a.y;
    As[ac + 2][ar] = a.z;
    As[ac + 3][ar] = a.w;
    float4 b = *(const float4*)(B + (size_t)(k0 + br) * N + bn + bc);
    Bs[br][bc + 0] = b.x;
    Bs[br][bc + 1] = b.y;
    Bs[br][bc + 2] = b.z;
    Bs[br][bc + 3] = b.w;
    __syncthreads();
#pragma unroll
    for (int kk = 0; kk < 16; ++kk) {
      float av[4], bv[4];
#pragma unroll
      for (int i = 0; i < 4; ++i) av[i] = As[kk][tm + i];
#pragma unroll
      for (int j = 0; j < 4; ++j) bv[j] = Bs[kk][tn + j];
#pragma unroll
      for (int i = 0; i < 4; ++i)
#pragma unroll
        for (int j = 0; j < 4; ++j) acc[i][j] = fmaf(av[i], bv[j], acc[i][j]);
    }
    __syncthreads();
  }
#pragma unroll
  for (int i = 0; i < 4; ++i) {
    int row = bm + tm + i;
    if (row < M) {
#pragma unroll
      for (int j = 0; j < 4; ++j) {
        int col = bn + tn + j;
        float v = acc[i][j] + (bias ? bias[col] : 0.f);
        if (OUT_BF16)
          ((unsigned short*)Cv)[(size_t)row * N + col] = f32_to_bf16_bits(v);
        else
          ((float*)Cv)[(size_t)row * N + col] = v;
      }
    }
  }
}

// B2[d][r*2+cls] = W2[r][d][cls] ; B2[d][16+cls] = root2[d][cls]
__global__ void build_B2(const float* __restrict__ W2, const float* __restrict__ root2,
                         float* __restrict__ Bm) {
  int idx = blockIdx.x * blockDim.x + threadIdx.x;
  if (idx >= 128 * H2COLS) return;
  int d = idx / H2COLS, c = idx - d * H2COLS;
  Bm[idx] = (c < 16) ? W2[((size_t)(c >> 1) * 128 + d) * 2 + (c & 1)]
                     : root2[(size_t)d * 2 + (c - 16)];
}

// ---------------- edge kernels (all indices clamped: wrong answer beats a fault) ----
__global__ void count_edges(const int* __restrict__ ei, const int* __restrict__ et,
                            float* __restrict__ cnt) {
  int e = blockIdx.x * blockDim.x + threadIdx.x;
  int stride = gridDim.x * blockDim.x;
  for (; e < NEDGE; e += stride) {
    unsigned d = (unsigned)ei[NEDGE + e]; if (d >= NNODES) d = 0;
    unsigned t = (unsigned)et[e];         if (t >= NREL)  t = 0;
    atomicAdd(cnt + (size_t)d * NREL + t, 1.0f);
  }
}

// one wave per edge of relation r: agg1[dst] += hr[src] / cnt[dst, r]
__global__ void edge_pass1_rel(const int* __restrict__ ei, const int* __restrict__ et,
                               const float* __restrict__ cnt,
                               const unsigned short* __restrict__ hr,
                               float* __restrict__ agg1, int r) {
  int gw = (blockIdx.x * blockDim.x + threadIdx.x) >> 6;
  int lane = threadIdx.x & 63;
  int nw = (gridDim.x * blockDim.x) >> 6;
  for (int e = gw; e < NEDGE; e += nw) {
    unsigned t = (unsigned)et[e]; if (t >= NREL) t = 0;
    if ((int)t != r) continue;
    unsigned s = (unsigned)ei[e];         if (s >= NNODES) s = 0;
    unsigned d = (unsigned)ei[NEDGE + e]; if (d >= NNODES) d = 0;
    float w = 1.0f / fmaxf(cnt[(size_t)d * NREL + t], 1.0f);
    unsigned u = ((const unsigned*)(hr + (size_t)s * 128))[lane];
    float lo = bf16_bits_to_f32((unsigned short)(u & 0xffffu));
    float hi = bf16_bits_to_f32((unsigned short)(u >> 16));
    float* dst = agg1 + (size_t)d * 128 + lane * 2;
    atomicAdd(dst, lo * w);
    atomicAdd(dst + 1, hi * w);
  }
}

// x1 = relu(agg1 + b1) in place (root contribution already in agg1 via GEMM init)
__global__ void epi1(float* __restrict__ agg1, const float* __restrict__ b1) {
  int idx = blockIdx.x * blockDim.x + threadIdx.x;
  if (idx >= NNODES * 128) return;
  float v = agg1[idx] + b1[idx & 127];
  agg1[idx] = v > 0.f ? v : 0.f;
}

// h2[n, 0:18] = x1[n,:] @ B2   (wave per node)
__global__ __launch_bounds__(256) void l2_transform(const float* __restrict__ x1,
                                                    const float* __restrict__ B2,
                                                    float* __restrict__ h2) {
  __shared__ float sB[128 * H2COLS];
  for (int i = threadIdx.x; i < 128 * H2COLS; i += 256) sB[i] = B2[i];
  __syncthreads();
  int lane = threadIdx.x & 63;
  int wid = (blockIdx.x * blockDim.x + threadIdx.x) >> 6;
  int nw = (gridDim.x * blockDim.x) >> 6;
  for (int n = wid; n < NNODES; n += nw) {
    float a0 = x1[(size_t)n * 128 + lane];
    float a1 = x1[(size_t)n * 128 + 64 + lane];
    float p[H2COLS];
#pragma unroll
    for (int c = 0; c < H2COLS; ++c)
      p[c] = a0 * sB[lane * H2COLS + c] + a1 * sB[(lane + 64) * H2COLS + c];
#pragma unroll
    for (int c = 0; c < H2COLS; ++c)
#pragma unroll
      for (int off = 32; off; off >>= 1) p[c] += __shfl_xor(p[c], off, 64);
    if (lane == 0) {
#pragma unroll
      for (int c = 0; c < H2COLS; ++c) h2[(size_t)n * H2COLS + c] = p[c];
    }
  }
}

__global__ void edge_pass2(const int* __restrict__ ei, const int* __restrict__ et,
                           const float* __restrict__ cnt, const float* __restrict__ h2,
                           float* __restrict__ agg2) {
  int e = blockIdx.x * blockDim.x + threadIdx.x;
  int stride = gridDim.x * blockDim.x;
  for (; e < NEDGE; e += stride) {
    unsigned s = (unsigned)ei[e];         if (s >= NNODES) s = 0;
    unsigned d = (unsigned)ei[NEDGE + e]; if (d >= NNODES) d = 0;
    unsigned t = (unsigned)et[e];         if (t >= NREL) t = 0;
    float w = 1.0f / fmaxf(cnt[(size_t)d * NREL + t], 1.0f);
    float v0 = h2[(size_t)s * H2COLS + t * 2];
    float v1 = h2[(size_t)s * H2COLS + t * 2 + 1];
    atomicAdd(agg2 + (size_t)d * 2, v0 * w);
    atomicAdd(agg2 + (size_t)d * 2 + 1, v1 * w);
  }
}

__global__ void out_kernel(const float* __restrict__ agg2, const float* __restrict__ h2,
                           const float* __restrict__ b2, float* __restrict__ out) {
  int n = blockIdx.x * blockDim.x + threadIdx.x;
  if (n >= NNODES) return;
  float z0 = agg2[(size_t)n * 2 + 0] + h2[(size_t)n * H2COLS + 16] + b2[0];
  float z1 = agg2[(size_t)n * 2 + 1] + h2[(size_t)n * H2COLS + 17] + b2[1];
  float m = fmaxf(z0, z1);
  float l = m + logf(expf(z0 - m) + expf(z1 - m));
  out[(size_t)n * 2 + 0] = z0 - l;
  out[(size_t)n * 2 + 1] = z1 - l;
}

__global__ void fill_sentinel(float* __restrict__ out, int n, float v) {
  int i = blockIdx.x * blockDim.x + threadIdx.x;
  if (i < n) out[i] = v;
}

// -----------------------------------------------------------------------------------
extern "C" void kernel_launch(void* const* d_in, const int* in_sizes, int n_in,
                              void* d_out, int out_size, void* d_ws, size_t ws_size,
                              hipStream_t stream) {
  const float* x_user = (const float*)d_in[0];
  const float* x_food = (const float*)d_in[1];
  const float* x_ing  = (const float*)d_in[2];
  const float* x_cat  = (const float*)d_in[3];
  const float* x_hab  = (const float*)d_in[4];
  const float* Wu = (const float*)d_in[5];  const float* bu  = (const float*)d_in[6];
  const float* Wf = (const float*)d_in[7];  const float* bfo = (const float*)d_in[8];
  const float* Wi = (const float*)d_in[9];  const float* bi  = (const float*)d_in[10];
  const float* Wc = (const float*)d_in[11]; const float* bc  = (const float*)d_in[12];
  const float* Wh = (const float*)d_in[13]; const float* bh  = (const float*)d_in[14];
  const float* W1 = (const float*)d_in[15]; const float* root1 = (const float*)d_in[16];
  const float* b1 = (const float*)d_in[17];
  const float* W2 = (const float*)d_in[18]; const float* root2 = (const float*)d_in[19];
  const float* b2 = (const float*)d_in[20];
  const int* ei = (const int*)d_in[21];   // [2, NEDGE]: row0 = src, row1 = dst
  const int* et = (const int*)d_in[22];   // [NEDGE]

  // ---- workspace layout (~152 MB) ----
  char* ws = (char*)d_ws;
  size_t off = 0;
  float* x_all = (float*)(ws + off);  off += alignup((size_t)NNODES * 128 * 4);   // 58.9 MB
  float* agg1  = (float*)(ws + off);  off += alignup((size_t)NNODES * 128 * 4);   // 58.9 MB
  unsigned short* hr = (unsigned short*)(ws + off);
  off += alignup((size_t)NNODES * 128 * 2);                                       // 29.4 MB
  float* cnt  = (float*)(ws + off);   off += alignup((size_t)NNODES * NREL * 4);  // 3.7 MB
  float* Bm2  = (float*)(ws + off);   off += alignup((size_t)128 * H2COLS * 4);
  float* agg2 = (float*)(ws + off);   off += alignup((size_t)NNODES * 2 * 4);     // 0.9 MB
  size_t needed = off;
  float* x1 = agg1;        // alias: epi1 is in-place
  float* h2 = (float*)hr;  // alias: hr dead after edge passes; 8.3 MB < 29.4 MB
  (void)in_sizes; (void)n_in; (void)out_size;

  dim3 blk(256);
  if (ws_size < needed) {
    // diagnostic: absmax ~777 next round => workspace too small
    fill_sentinel<<<(out_size + 255) / 256, blk, 0, stream>>>((float*)d_out, out_size, -777.0f);
    return;
  }

  hipMemsetAsync(cnt, 0, (size_t)NNODES * NREL * 4, stream);
  hipMemsetAsync(agg2, 0, (size_t)NNODES * 2 * 4, stream);

  // ---- feature projections into x_all ----
  {
    dim3 g(2, (NU + 63) / 64);
    gemm64<false><<<g, blk, 0, stream>>>(x_user, Wu, bu, (void*)(x_all + (size_t)0 * 128), NU, 128, 256);
  }
  {
    dim3 g(2, (NFOOD + 63) / 64);
    gemm64<false><<<g, blk, 0, stream>>>(x_food, Wf, bfo, (void*)(x_all + (size_t)NU * 128), NFOOD, 128, 512);
  }
  {
    dim3 g(2, (NING + 63) / 64);
    gemm64<false><<<g, blk, 0, stream>>>(x_ing, Wi, bi, (void*)(x_all + (size_t)(NU + NFOOD) * 128), NING, 128, 128);
  }
  {
    dim3 g(2, (NCAT + 63) / 64);
    gemm64<false><<<g, blk, 0, stream>>>(x_cat, Wc, bc, (void*)(x_all + (size_t)(NU + NFOOD + NING) * 128), NCAT, 128, 64);
  }
  {
    dim3 g(2, (NHAB + 63) / 64);
    gemm64<false><<<g, blk, 0, stream>>>(x_hab, Wh, bh, (void*)(x_all + (size_t)(NU + NFOOD + NING + NCAT) * 128), NHAB, 128, 64);
  }

  count_edges<<<2048, blk, 0, stream>>>(ei, et, cnt);

  // agg1 = x_all @ root1  (root contribution; also serves as the accumulator init)
  {
    dim3 g(2, (NNODES + 63) / 64);
    gemm64<false><<<g, blk, 0, stream>>>(x_all, root1, nullptr, (void*)agg1, NNODES, 128, 128);
  }

  // ---- layer 1, one relation at a time: hr = x_all @ W1[r]; scatter into agg1 ----
  for (int r = 0; r < NREL; ++r) {
    dim3 g(2, (NNODES + 63) / 64);
    gemm64<true><<<g, blk, 0, stream>>>(x_all, W1 + (size_t)r * 128 * 128, nullptr,
                                        (void*)hr, NNODES, 128, 128);
    edge_pass1_rel<<<4096, blk, 0, stream>>>(ei, et, cnt, hr, agg1, r);
  }

  epi1<<<(NNODES * 128 + 255) / 256, blk, 0, stream>>>(agg1, b1);

  build_B2<<<(128 * H2COLS + 255) / 256, blk, 0, stream>>>(W2, root2, Bm2);
  l2_transform<<<2048, blk, 0, stream>>>(x1, Bm2, h2);
  edge_pass2<<<2048, blk, 0, stream>>>(ei, et, cnt, h2, agg2);
  out_kernel<<<(NNODES + 255) / 256, blk, 0, stream>>>(agg2, h2, b2, (float*)d_out);
}